// Round 7
// baseline (3963.593 us; speedup 1.0000x reference)
//
#include <hip/hip_runtime.h>
#include <cstdint>
#include <cstddef>

typedef short bf16x8 __attribute__((ext_vector_type(8)));
typedef float f32x4 __attribute__((ext_vector_type(4)));

__device__ __forceinline__ unsigned short f2bf(float f) {
    union { float f; uint32_t u; } v; v.f = f;
    uint32_t r = v.u + 0x7FFFu + ((v.u >> 16) & 1u);   // round-to-nearest-even
    return (unsigned short)(r >> 16);
}

__device__ __forceinline__ float bf2f(unsigned short u) {
    union { uint32_t u; float f; } v; v.u = (uint32_t)u << 16;
    return v.f;
}

// ---------------- prep: cast X to bf16  +  transpose-cast B ----------------

__global__ void prep_kernel(const float* __restrict__ X,
                            unsigned short* __restrict__ Xbf, int n4,
                            const float* __restrict__ B,
                            unsigned short* __restrict__ Bt, int H,
                            int castBlocks) {
    if ((int)blockIdx.x < castBlocks) {
        int i = blockIdx.x * 256 + threadIdx.x;
        if (i < n4) {
            float4 v = ((const float4*)X)[i];
            ushort4 o;
            o.x = f2bf(v.x); o.y = f2bf(v.y); o.z = f2bf(v.z); o.w = f2bf(v.w);
            ((ushort4*)Xbf)[i] = o;
        }
        return;
    }
    __shared__ float tile[32][33];
    int tb = blockIdx.x - castBlocks;
    int tilesPerRow = H / 32;
    int bx = (tb % tilesPerRow) * 32;   // n tile
    int by = (tb / tilesPerRow) * 32;   // k tile
    int tx = threadIdx.x & 31, ty = threadIdx.x >> 5;   // (32,8)
#pragma unroll
    for (int i = 0; i < 32; i += 8)
        tile[ty + i][tx] = B[(size_t)(by + ty + i) * H + bx + tx];
    __syncthreads();
#pragma unroll
    for (int i = 0; i < 32; i += 8)
        Bt[(size_t)(bx + ty + i) * H + by + tx] = f2bf(tile[tx][ty + i]);
}

// ---------------- tier-1: fused full-K GEMM + in-block scan (v5) ------------
// Config table from r2-r6: co-resident blocks are the ONLY mechanism that
// hides the per-step stage drain (v2: 2 blk/CU = 50us; v1/v3/v4 @ 1 blk/CU =
// 57/57/67us regardless of schedule sophistication). v2's limit is its 64x64
// wave tiles (32 FLOP/LDS-byte -> 44us LDS floor). v5 keeps v2's EXACT
// staging layout (A 136 rows + B 128 rows = 33 chunks, proven XOR swizzle)
// but uses 2 waves of 64x128 tiles (acc[4][8], 12-13 b128 per 36 MFMA = 42.7
// FLOP/byte) -> 128 threads/block, LDS 35904 B -> 4 blocks/CU, 8 waves/CU.
// Single-buffer tier-2 schedule (stage -> barrier -> compute -> barrier);
// 4 independent blocks desync to cover each other's drains.
// Warm-up: wave w does 4 extra MFMAs/kk (aw x bfr[w*4+j], +1 read); wacc
// rows 0..7 = warm rows (global m0-8..m0-1), rows 8..15 discarded.
// Epilogue: S bf16 in LDS stride 132 (v2-proven, 0 conflicts), 128 cols x
// 128-row in-LDS scan, coalesced fp32 out.

__global__ __launch_bounds__(128, 2) void gemm_scan_fused(
    const unsigned short* __restrict__ A,
    const unsigned short* __restrict__ Bt,
    const float* __restrict__ Ad,
    float* __restrict__ out,
    int M, int N, int K, int gridMt)
{
    extern __shared__ char smem[];   // 35904 B (staging 33792 | epilogue 35904)

    const int tid  = threadIdx.x;
    const int wave = tid >> 6;          // 0..1
    const int lane = tid & 63;

    int b = blockIdx.x;
    int mt, nt;
    if ((gridMt & 7) == 0) {
        int x = b & 7, g = b >> 3;
        int mPerX = gridMt >> 3;
        mt = x * mPerX + (g % mPerX);
        nt = g / mPerX;
    } else {
        mt = b % gridMt;
        nt = b / gridMt;
    }
    const int m0 = mt * 128;
    const int n0 = nt * 128;

    const int srow = lane >> 3;
    const int scol = ((lane & 7) ^ srow) * 8;
    const int quad = lane >> 4;
    const int l16  = lane & 15;
    const int s7   = l16 & 7;
    const int koff0 = (quad ^ s7) * 16;
    const int koff1 = ((quad + 4) ^ s7) * 16;
    const int hi8  = l16 >> 3;

    f32x4 acc[4][8];
#pragma unroll
    for (int i = 0; i < 4; ++i)
#pragma unroll
        for (int j = 0; j < 8; ++j)
            acc[i][j] = (f32x4){0.f, 0.f, 0.f, 0.f};
    f32x4 wacc[4];
#pragma unroll
    for (int j = 0; j < 4; ++j)
        wacc[j] = (f32x4){0.f, 0.f, 0.f, 0.f};

    const int NT = K >> 6;

    // chunk t: t<17 -> A rows m0-8+t*8+srow (clamped); t>=17 -> B rows
    // n0+(t-17)*8+srow. lane l -> slot l*16B, global colblk (l&7)^(l>>3).
    // (identical layout to r4-verified v2)
    const unsigned short* const Ag = A  - (size_t)8 * K;   // row -8 base
    const unsigned short* const Bg = Bt + (size_t)n0 * K;

    for (int t = 0; t < NT; ++t) {
        const int k0 = t * 64;
#pragma unroll
        for (int i = 0; i < 17; ++i) {
            const int c = wave + i * 2;
            if (c < 33) {
                const unsigned short* g;
                if (c < 17) {
                    int gr = m0 - 8 + c * 8 + srow;
                    if (gr < 0) gr = 0;                 // mt==0 warm clamp
                    g = A + (size_t)gr * K + (k0 + scol);
                } else {
                    g = Bg + (size_t)((c - 17) * 8 + srow) * K + (k0 + scol);
                }
                __builtin_amdgcn_global_load_lds(
                    (const __attribute__((address_space(1))) void*)g,
                    (__attribute__((address_space(3))) void*)
                        (smem + c * 1024 + lane * 16),
                    16, 0, 0);
            }
        }
        __syncthreads();                 // drains vmcnt; buf visible

#pragma unroll
        for (int kk = 0; kk < 2; ++kk) {
            const int co = kk ? koff1 : koff0;
            bf16x8 af[4], bfr[8], aw;
            aw = *(const bf16x8*)(smem + hi8 * 1024 + s7 * 128 + co);
#pragma unroll
            for (int im = 0; im < 4; ++im)
                af[im] = *(const bf16x8*)(smem +
                    (1 + wave * 8 + im * 2 + hi8) * 1024 + s7 * 128 + co);
#pragma unroll
            for (int in = 0; in < 8; ++in)
                bfr[in] = *(const bf16x8*)(smem +
                    (17 + in * 2 + hi8) * 1024 + s7 * 128 + co);
#pragma unroll
            for (int im = 0; im < 4; ++im)
#pragma unroll
                for (int in = 0; in < 8; ++in)
                    acc[im][in] = __builtin_amdgcn_mfma_f32_16x16x32_bf16(
                        af[im], bfr[in], acc[im][in], 0, 0, 0);
#pragma unroll
            for (int j = 0; j < 4; ++j)   // warm: wave w covers cols w*64..
                wacc[j] = __builtin_amdgcn_mfma_f32_16x16x32_bf16(
                    aw, bfr[wave * 4 + j], wacc[j], 0, 0, 0);
        }
        __syncthreads();                 // reads done -> next stage may clobber
    }

    // ---- epilogue: S (bf16) -> LDS rows 0..135 stride 132 ----
    // LDS row l = global row m0-8+l (rows 0..7 warm).
    unsigned short* Sl = (unsigned short*)smem;
#pragma unroll
    for (int im = 0; im < 4; ++im)
#pragma unroll
        for (int in = 0; in < 8; ++in) {
            const int col = in * 16 + l16;
#pragma unroll
            for (int r = 0; r < 4; ++r) {
                const int row = 8 + wave * 64 + im * 16 + quad * 4 + r;
                Sl[row * 132 + col] = f2bf(acc[im][in][r]);
            }
        }
    if (quad < 2) {                      // warm rows 0..7 (wacc rows 0..7)
#pragma unroll
        for (int j = 0; j < 4; ++j) {
            const int col = wave * 64 + j * 16 + l16;
#pragma unroll
            for (int r = 0; r < 4; ++r)
                Sl[(quad * 4 + r) * 132 + col] = f2bf(wacc[j][r]);
        }
    }
    __syncthreads();

    // ---- in-block scan: 128 cols x 128 rows ----
    const int c = tid;                   // 0..127
    const float aa = Ad[n0 + c];
    float y = 0.f;
    if (mt != 0) {
#pragma unroll
        for (int i = 0; i < 8; ++i)      // warm rows 0..7
            y = fmaf(aa, y, bf2f(Sl[i * 132 + c]));
    }
    const size_t ob = (size_t)m0 * N + n0 + c;
    const unsigned short* Sr = Sl + 8 * 132 + c;
    for (int t = 0; t < 128; ++t) {
        y = fmaf(aa, y, bf2f(Sr[t * 132]));
        out[ob + (size_t)t * N] = y;
    }
}

// ---------------- tier-2 GEMM: 256x128, split-K=2, bf16 out (proven) --------

__global__ __launch_bounds__(256, 2) void gemm_sk_bf16out(
    const unsigned short* __restrict__ A,
    const unsigned short* __restrict__ Bt,
    unsigned short* __restrict__ S0, unsigned short* __restrict__ S1,
    int M, int N, int K, int gridM, int gridN)
{
    __shared__ __attribute__((aligned(16))) unsigned short sA[256 * 64];
    __shared__ __attribute__((aligned(16))) unsigned short sB[128 * 64];

    const int tid  = threadIdx.x;
    const int wave = tid >> 6;
    const int lane = tid & 63;

    int b = blockIdx.x;
    int mt, nt, kt;
    if ((gridM & 7) == 0) {
        int x = b & 7, g = b >> 3;
        int mPerX = gridM >> 3;
        int ml = g % mPerX, g2 = g / mPerX;
        nt = g2 % gridN;
        kt = g2 / gridN;
        mt = x * mPerX + ml;
    } else {
        mt = b % gridM;
        nt = (b / gridM) % gridN;
        kt = b / (gridM * gridN);
    }
    const int m0 = mt * 256;
    const int n0 = nt * 128;
    const int ksize = K / 2;
    const int kbase = kt * ksize;

    const int srow = lane >> 3;
    const int scol = ((lane & 7) ^ srow) * 8;

    const int quad = lane >> 4;
    const int l16  = lane & 15;
    const int wm = wave >> 1;
    const int wn = wave & 1;
    const int s7 = l16 & 7;
    const int c0 = (quad ^ s7) * 16;
    const int c1 = ((quad + 4) ^ s7) * 16;

    f32x4 acc[8][4];
#pragma unroll
    for (int i = 0; i < 8; ++i)
#pragma unroll
        for (int j = 0; j < 4; ++j)
            acc[i][j] = (f32x4){0.f, 0.f, 0.f, 0.f};

    const unsigned short* Ab = A  + (size_t)m0 * K;
    const unsigned short* Bb = Bt + (size_t)n0 * K;

    const int rA = (wm * 16 + (l16 >> 3)) * 1024 + s7 * 128;
    const int rB = (wn * 8  + (l16 >> 3)) * 1024 + s7 * 128;

    for (int k0 = kbase; k0 < kbase + ksize; k0 += 64) {
#pragma unroll
        for (int i = 0; i < 8; ++i) {
            const int t = wave * 8 + i;
            const unsigned short* ga = Ab + (size_t)(t * 8 + srow) * K + (k0 + scol);
            __builtin_amdgcn_global_load_lds(
                (const __attribute__((address_space(1))) void*)ga,
                (__attribute__((address_space(3))) void*)(sA + t * 512),
                16, 0, 0);
        }
#pragma unroll
        for (int i = 0; i < 4; ++i) {
            const int t = wave * 4 + i;
            const unsigned short* gb = Bb + (size_t)(t * 8 + srow) * K + (k0 + scol);
            __builtin_amdgcn_global_load_lds(
                (const __attribute__((address_space(1))) void*)gb,
                (__attribute__((address_space(3))) void*)(sB + t * 512),
                16, 0, 0);
        }
        __syncthreads();

#pragma unroll
        for (int kk = 0; kk < 2; ++kk) {
            const int co = kk ? c1 : c0;
            bf16x8 af[8], bfr[4];
#pragma unroll
            for (int im = 0; im < 8; ++im)
                af[im] = *(const bf16x8*)((const char*)sA + rA + im * 2048 + co);
#pragma unroll
            for (int in = 0; in < 4; ++in)
                bfr[in] = *(const bf16x8*)((const char*)sB + rB + in * 2048 + co);
#pragma unroll
            for (int im = 0; im < 8; ++im)
#pragma unroll
                for (int in = 0; in < 4; ++in)
                    acc[im][in] = __builtin_amdgcn_mfma_f32_16x16x32_bf16(
                        af[im], bfr[in], acc[im][in], 0, 0, 0);
        }
        __syncthreads();
    }

    unsigned short* __restrict__ S = (kt == 0) ? S0 : S1;
#pragma unroll
    for (int im = 0; im < 8; ++im) {
#pragma unroll
        for (int in = 0; in < 4; ++in) {
            int col = n0 + wn * 64 + in * 16 + l16;
#pragma unroll
            for (int r = 0; r < 4; ++r) {
                int row = m0 + wm * 128 + im * 16 + quad * 4 + r;
                S[(size_t)row * N + col] = f2bf(acc[im][in][r]);
            }
        }
    }
}

// ---------------- mid-tier GEMM (fp32 out, non-split; round-3 proven) -------

__device__ __forceinline__ void stage_tile128(
    const unsigned short* __restrict__ Ab, const unsigned short* __restrict__ Bb,
    unsigned short* sAp, unsigned short* sBp,
    int wave, int srow, int scol, int k0, int K)
{
#pragma unroll
    for (int i = 0; i < 4; ++i) {
        const int t = wave * 4 + i;
        const unsigned short* ga = Ab + (size_t)(t * 8 + srow) * K + (k0 + scol);
        __builtin_amdgcn_global_load_lds(
            (const __attribute__((address_space(1))) void*)ga,
            (__attribute__((address_space(3))) void*)(sAp + t * 512),
            16, 0, 0);
        const unsigned short* gb = Bb + (size_t)(t * 8 + srow) * K + (k0 + scol);
        __builtin_amdgcn_global_load_lds(
            (const __attribute__((address_space(1))) void*)gb,
            (__attribute__((address_space(3))) void*)(sBp + t * 512),
            16, 0, 0);
    }
}

__global__ __launch_bounds__(256, 4) void gemm_f32out(
    const unsigned short* __restrict__ A,
    const unsigned short* __restrict__ Bt,
    float* __restrict__ C, int M, int N, int K, int gridM)
{
    __shared__ __attribute__((aligned(16))) unsigned short sA[128 * 64];
    __shared__ __attribute__((aligned(16))) unsigned short sB[128 * 64];

    const int tid  = threadIdx.x;
    const int wave = tid >> 6;
    const int lane = tid & 63;

    int b = blockIdx.x;
    int mt, nt;
    if ((gridM & 7) == 0) {
        int x = b & 7, g = b >> 3;
        int mPerX = gridM >> 3;
        mt = x * mPerX + (g % mPerX);
        nt = g / mPerX;
    } else {
        mt = b % gridM;
        nt = b / gridM;
    }
    const int m0 = mt * 128;
    const int n0 = nt * 128;

    const int srow = lane >> 3;
    const int scol = ((lane & 7) ^ srow) * 8;
    const int quad = lane >> 4;
    const int l16  = lane & 15;
    const int wm = wave >> 1;
    const int wn = wave & 1;
    const int s7 = l16 & 7;
    const int rbaseA = (wm * 8 + (l16 >> 3)) * 1024 + s7 * 128;
    const int rbaseB = (wn * 8 + (l16 >> 3)) * 1024 + s7 * 128;
    const int coff0 = (quad ^ s7) * 16;
    const int coff1 = ((quad + 4) ^ s7) * 16;

    f32x4 acc[4][4];
#pragma unroll
    for (int i = 0; i < 4; ++i)
#pragma unroll
        for (int j = 0; j < 4; ++j)
            acc[i][j] = (f32x4){0.f, 0.f, 0.f, 0.f};

    const unsigned short* Ab = A  + (size_t)m0 * K;
    const unsigned short* Bb = Bt + (size_t)n0 * K;

    for (int k0 = 0; k0 < K; k0 += 64) {
        stage_tile128(Ab, Bb, sA, sB, wave, srow, scol, k0, K);
        __syncthreads();
        bf16x8 af[2][4], bfr[2][4];
#pragma unroll
        for (int t = 0; t < 4; ++t) {
            const char* pa = (const char*)sA + rbaseA + t * 2048;
            af[0][t]  = *(const bf16x8*)(pa + coff0);
            af[1][t]  = *(const bf16x8*)(pa + coff1);
            const char* pb = (const char*)sB + rbaseB + t * 2048;
            bfr[0][t] = *(const bf16x8*)(pb + coff0);
            bfr[1][t] = *(const bf16x8*)(pb + coff1);
        }
#pragma unroll
        for (int kk = 0; kk < 2; ++kk)
#pragma unroll
            for (int im = 0; im < 4; ++im)
#pragma unroll
                for (int in = 0; in < 4; ++in)
                    acc[im][in] = __builtin_amdgcn_mfma_f32_16x16x32_bf16(
                        af[kk][im], bfr[kk][in], acc[im][in], 0, 0, 0);
        __syncthreads();
    }

#pragma unroll
    for (int im = 0; im < 4; ++im)
#pragma unroll
        for (int in = 0; in < 4; ++in) {
            int col = n0 + wn * 64 + in * 16 + l16;
#pragma unroll
            for (int r = 0; r < 4; ++r) {
                int row = m0 + wm * 64 + im * 16 + quad * 4 + r;
                C[(size_t)row * N + col] = acc[im][in][r];
            }
        }
}

// ---------------- scan (split-K fallback path) ----------------

__global__ void scan_splitk_bf16(const unsigned short* __restrict__ S0,
                                 const unsigned short* __restrict__ S1,
                                 const float* __restrict__ a_diag,
                                 float* __restrict__ out,
                                 int H2, int chunk) {
    int tid = blockIdx.x * blockDim.x + threadIdx.x;
    int hp = tid % H2, c = tid / H2;
    float2 av = ((const float2*)a_diag)[hp];
    const ushort2* S0v = (const ushort2*)S0;
    const ushort2* S1v = (const ushort2*)S1;
    float2* outv = (float2*)out;

    float y0 = 0.f, y1 = 0.f;
    if (c > 0) {
        size_t r0 = (size_t)c * chunk - 8;
#pragma unroll
        for (int i = 0; i < 8; ++i) {
            size_t idx = (r0 + i) * H2 + hp;
            ushort2 u = S0v[idx], w = S1v[idx];
            y0 = fmaf(av.x, y0, bf2f(u.x) + bf2f(w.x));
            y1 = fmaf(av.y, y1, bf2f(u.y) + bf2f(w.y));
        }
    }
    size_t idx = (size_t)c * chunk * H2 + hp;
    ushort2 u = S0v[idx], w = S1v[idx];
    for (int t = 0; t < chunk - 1; ++t) {
        size_t idx2 = idx + H2;
        ushort2 un = S0v[idx2], wn = S1v[idx2];
        y0 = fmaf(av.x, y0, bf2f(u.x) + bf2f(w.x));
        y1 = fmaf(av.y, y1, bf2f(u.y) + bf2f(w.y));
        outv[idx] = make_float2(y0, y1);
        u = un; w = wn; idx = idx2;
    }
    y0 = fmaf(av.x, y0, bf2f(u.x) + bf2f(w.x));
    y1 = fmaf(av.y, y1, bf2f(u.y) + bf2f(w.y));
    outv[idx] = make_float2(y0, y1);
}

// ---------------- mid-tier scan (fp32 S in out, in-place) --------------

__global__ void scan_init_kernel(const float* __restrict__ S,
                                 const float* __restrict__ a_diag,
                                 float* __restrict__ yinit,
                                 int H, int chunk, int W) {
    int tid = blockIdx.x * blockDim.x + threadIdx.x;
    int h = tid % H, c = tid / H;
    float a = a_diag[h];
    float y = 0.f;
    if (c > 0) {
        int t0 = c * chunk;
        for (int t = t0 - W; t < t0; ++t)
            y = fmaf(a, y, S[(size_t)t * H + h]);
    }
    yinit[(size_t)c * H + h] = y;
}

__global__ void scan_run_kernel(const float* __restrict__ yinit,
                                const float* __restrict__ a_diag,
                                float* __restrict__ out,
                                int H, int chunk) {
    int tid = blockIdx.x * blockDim.x + threadIdx.x;
    int h = tid % H, c = tid / H;
    float a = a_diag[h];
    float y = yinit[(size_t)c * H + h];
    size_t base = (size_t)c * chunk * H + h;
    float s = out[base];
#pragma unroll 4
    for (int t = 0; t < chunk - 1; ++t) {
        float snext = out[base + (size_t)(t + 1) * H];
        y = fmaf(a, y, s);
        out[base + (size_t)t * H] = y;
        s = snext;
    }
    y = fmaf(a, y, s);
    out[base + (size_t)(chunk - 1) * H] = y;
}

// ---------------- fallback (tiny ws): correct but slow ----------------

__global__ void gemm_fallback(const float* __restrict__ X, const float* __restrict__ B,
                              float* __restrict__ C, int M, int N, int K) {
    __shared__ float sA[16][17];
    __shared__ float sB[16][17];
    int tx = threadIdx.x, ty = threadIdx.y;
    int row = blockIdx.y * 16 + ty, col = blockIdx.x * 16 + tx;
    float acc = 0.f;
    for (int k0 = 0; k0 < K; k0 += 16) {
        sA[ty][tx] = (row < M && k0 + tx < K) ? X[(size_t)row * K + k0 + tx] : 0.f;
        sB[ty][tx] = (k0 + ty < K && col < N) ? B[(size_t)(k0 + ty) * N + col] : 0.f;
        __syncthreads();
#pragma unroll
        for (int kk = 0; kk < 16; ++kk) acc += sA[ty][kk] * sB[kk][tx];
        __syncthreads();
    }
    if (row < M && col < N) C[(size_t)row * N + col] = acc;
}

__global__ void scan_serial(float* __restrict__ out, const float* __restrict__ a_diag,
                            int T, int H) {
    int h = blockIdx.x * blockDim.x + threadIdx.x;
    if (h >= H) return;
    float a = a_diag[h], y = 0.f;
    for (int t = 0; t < T; ++t) {
        y = fmaf(a, y, out[(size_t)t * H + h]);
        out[(size_t)t * H + h] = y;
    }
}

// ---------------- launch ----------------

extern "C" void kernel_launch(void* const* d_in, const int* in_sizes, int n_in,
                              void* d_out, int out_size, void* d_ws, size_t ws_size,
                              hipStream_t stream) {
    const float* x = (const float*)d_in[0];   // (T,H)
    const float* a = (const float*)d_in[1];   // (H,)
    const float* b = (const float*)d_in[2];   // (H,H)
    float* out = (float*)d_out;               // (T,H)

    const int H = in_sizes[1];
    const int T = in_sizes[0] / H;
    const int M = T, N = H, K = H;

    const int CHUNK = 16, W = 12;

    size_t xbf_elems = (size_t)M * K;
    size_t bt_elems  = (size_t)N * K;
    size_t MN = (size_t)M * N;
    int nchunks = (T % CHUNK == 0) ? T / CHUNK : 0;

    size_t need_fused = (xbf_elems + bt_elems) * 2 + 256;
    size_t need_sk  = (xbf_elems + bt_elems + 2 * MN) * 2 + 256;
    size_t need_mid = xbf_elems * 2 + bt_elems * 2 + 256;

    bool shape_ok = (M % 128 == 0) && (N % 128 == 0) && (K % 128 == 0) &&
                    (H % 32 == 0) && nchunks > 0 && ((xbf_elems % 4) == 0) &&
                    (((size_t)nchunks * H) % 256 == 0);
    int gridMf = M / 128;
    int gridM  = (M % 256 == 0) ? M / 256 : 0;
    int gridN  = N / 128;

    int n4 = (int)(xbf_elems / 4);
    int castBlocks = (n4 + 255) / 256;
    int transBlocks = (H % 32 == 0) ? (H / 32) * (H / 32) : 0;

    int H2 = H / 2;
    size_t nth2 = (size_t)nchunks * H2;

    bool fused_ok = (M % 128 == 0) && (N % 128 == 0) && (K % 64 == 0) &&
                    (K >= 128) && (H % 32 == 0) && ((xbf_elems % 4) == 0) &&
                    ws_size >= need_fused;

    if (fused_ok) {
        // tier-1: fused full-K GEMM + in-block scan (no S materialization)
        unsigned short* Xbf = (unsigned short*)d_ws;
        unsigned short* Bt  = Xbf + xbf_elems;

        prep_kernel<<<castBlocks + transBlocks, 256, 0, stream>>>(
            x, Xbf, n4, b, Bt, H, castBlocks);

        gemm_scan_fused<<<(M / 128) * (N / 128), 128, 35904, stream>>>(
            Xbf, Bt, a, out, M, N, K, M / 128);
    } else if (shape_ok && gridM > 0 && (gridM % 8 == 0) && (H % 4 == 0) &&
               (nth2 % 256 == 0) && ws_size >= need_sk) {
        // tier-2: 256x128 tiles, split-K=2, bf16 partials, race-free scan
        unsigned short* Xbf = (unsigned short*)d_ws;
        unsigned short* Bt  = Xbf + xbf_elems;
        unsigned short* S0  = Bt + bt_elems;
        unsigned short* S1  = S0 + MN;

        prep_kernel<<<castBlocks + transBlocks, 256, 0, stream>>>(
            x, Xbf, n4, b, Bt, H, castBlocks);

        gemm_sk_bf16out<<<gridM * gridN * 2, 256, 0, stream>>>(
            Xbf, Bt, S0, S1, M, N, K, gridM, gridN);

        scan_splitk_bf16<<<(int)(nth2 / 256), 256, 0, stream>>>(
            S0, S1, a, out, H2, CHUNK);
    } else if (shape_ok && ws_size >= need_mid &&
               ((size_t)nchunks * H * 4 <= xbf_elems * 2)) {
        unsigned short* Xbf = (unsigned short*)d_ws;
        unsigned short* Bt  = Xbf + xbf_elems;
        float* yinit = (float*)d_ws;   // aliases Xbf: dead after gemm reads it

        prep_kernel<<<castBlocks + transBlocks, 256, 0, stream>>>(
            x, Xbf, n4, b, Bt, H, castBlocks);

        gemm_f32out<<<gridMf * gridN, 256, 0, stream>>>(
            Xbf, Bt, out, M, N, K, gridMf);

        int nth = nchunks * H;
        scan_init_kernel<<<nth / 256, 256, 0, stream>>>(out, a, yinit, H, CHUNK, W);
        scan_run_kernel<<<nth / 256, 256, 0, stream>>>(yinit, a, out, H, CHUNK);
    } else {
        dim3 tb(16, 16), tg((N + 15) / 16, (M + 15) / 16);
        gemm_fallback<<<tg, tb, 0, stream>>>(x, b, out, M, N, K);
        scan_serial<<<(H + 255) / 256, 256, 0, stream>>>(out, a, T, H);
    }
}

// Round 8
// 301.859 us; speedup vs baseline: 13.1306x; 13.1306x over previous
//
#include <hip/hip_runtime.h>
#include <cstdint>
#include <cstddef>

typedef short bf16x8 __attribute__((ext_vector_type(8)));
typedef float f32x4 __attribute__((ext_vector_type(4)));

__device__ __forceinline__ unsigned short f2bf(float f) {
    union { float f; uint32_t u; } v; v.f = f;
    uint32_t r = v.u + 0x7FFFu + ((v.u >> 16) & 1u);   // round-to-nearest-even
    return (unsigned short)(r >> 16);
}

__device__ __forceinline__ float bf2f(unsigned short u) {
    union { uint32_t u; float f; } v; v.u = (uint32_t)u << 16;
    return v.f;
}

// ---------------- prep: cast X to bf16  +  transpose-cast B ----------------

__global__ void prep_kernel(const float* __restrict__ X,
                            unsigned short* __restrict__ Xbf, int n4,
                            const float* __restrict__ B,
                            unsigned short* __restrict__ Bt, int H,
                            int castBlocks) {
    if ((int)blockIdx.x < castBlocks) {
        int i = blockIdx.x * 256 + threadIdx.x;
        if (i < n4) {
            float4 v = ((const float4*)X)[i];
            ushort4 o;
            o.x = f2bf(v.x); o.y = f2bf(v.y); o.z = f2bf(v.z); o.w = f2bf(v.w);
            ((ushort4*)Xbf)[i] = o;
        }
        return;
    }
    __shared__ float tile[32][33];
    int tb = blockIdx.x - castBlocks;
    int tilesPerRow = H / 32;
    int bx = (tb % tilesPerRow) * 32;   // n tile
    int by = (tb / tilesPerRow) * 32;   // k tile
    int tx = threadIdx.x & 31, ty = threadIdx.x >> 5;   // (32,8)
#pragma unroll
    for (int i = 0; i < 32; i += 8)
        tile[ty + i][tx] = B[(size_t)(by + ty + i) * H + bx + tx];
    __syncthreads();
#pragma unroll
    for (int i = 0; i < 32; i += 8)
        Bt[(size_t)(bx + ty + i) * H + by + tx] = f2bf(tile[tx][ty + i]);
}

// ---------------- tier-1: fused full-K GEMM + in-block scan (v5b) -----------
// v5 (r7) was sunk by rule #20: warm MFMA used bfr[wave*4+j] -- RUNTIME index
// into an ext_vector array -> whole bfr[8] demoted to scratch -> 1.09GB HBM
// scratch traffic, MfmaUtil 0.4%, 3.9ms. v5b: branch on wave (wave-uniform)
// with STATIC bfr indices; everything else identical.
// Geometry (r2-r6 config table): co-resident blocks are the only mechanism
// that hides per-step stage drains (v2: 2blk/CU = 50us; all 1blk/CU variants
// 57-67us). v5b: block 128x128, 2 waves of 64x128 tiles (acc[4][8], 42.7
// FLOP/LDS-byte), 128 thr/block, LDS 35904 B -> 4 blocks/CU, 8 waves/CU.
// Single-buffer tier-2 schedule; 4 independent blocks desync to cover each
// other's drains. Staging layout identical to r4-verified v2 (A 136 rows +
// B 128 rows = 33 chunks, proven XOR swizzle, 0 conflicts).
// Warm-up: wave w does 4 extra MFMAs/kk (aw x its 4 B-frags); wacc rows 0..7
// = warm rows (global m0-8..m0-1), rows 8..15 discarded. |a| <= 2^-5 ->
// 8-row replay reconstructs carry to ~1e-12.
// Epilogue: S bf16 in LDS stride 132, 128-col x 128-row in-LDS scan.

__global__ __launch_bounds__(128, 2) void gemm_scan_fused(
    const unsigned short* __restrict__ A,
    const unsigned short* __restrict__ Bt,
    const float* __restrict__ Ad,
    float* __restrict__ out,
    int M, int N, int K, int gridMt)
{
    extern __shared__ char smem[];   // 35904 B (staging 33792 | epilogue 35904)

    const int tid  = threadIdx.x;
    const int wave = tid >> 6;          // 0..1
    const int lane = tid & 63;

    int b = blockIdx.x;
    int mt, nt;
    if ((gridMt & 7) == 0) {
        int x = b & 7, g = b >> 3;
        int mPerX = gridMt >> 3;
        mt = x * mPerX + (g % mPerX);
        nt = g / mPerX;
    } else {
        mt = b % gridMt;
        nt = b / gridMt;
    }
    const int m0 = mt * 128;
    const int n0 = nt * 128;

    const int srow = lane >> 3;
    const int scol = ((lane & 7) ^ srow) * 8;
    const int quad = lane >> 4;
    const int l16  = lane & 15;
    const int s7   = l16 & 7;
    const int koff0 = (quad ^ s7) * 16;
    const int koff1 = ((quad + 4) ^ s7) * 16;
    const int hi8  = l16 >> 3;

    f32x4 acc[4][8];
#pragma unroll
    for (int i = 0; i < 4; ++i)
#pragma unroll
        for (int j = 0; j < 8; ++j)
            acc[i][j] = (f32x4){0.f, 0.f, 0.f, 0.f};
    f32x4 wacc[4];
#pragma unroll
    for (int j = 0; j < 4; ++j)
        wacc[j] = (f32x4){0.f, 0.f, 0.f, 0.f};

    const int NT = K >> 6;

    // chunk c: c<17 -> A rows m0-8+c*8+srow (clamped); c>=17 -> B rows
    // n0+(c-17)*8+srow. lane l -> slot l*16B, global colblk (l&7)^(l>>3).
    const unsigned short* const Bg = Bt + (size_t)n0 * K;

    for (int t = 0; t < NT; ++t) {
        const int k0 = t * 64;
#pragma unroll
        for (int i = 0; i < 17; ++i) {
            const int c = wave + i * 2;
            if (c < 33) {
                const unsigned short* g;
                if (c < 17) {
                    int gr = m0 - 8 + c * 8 + srow;
                    if (gr < 0) gr = 0;                 // mt==0 warm clamp
                    g = A + (size_t)gr * K + (k0 + scol);
                } else {
                    g = Bg + (size_t)((c - 17) * 8 + srow) * K + (k0 + scol);
                }
                __builtin_amdgcn_global_load_lds(
                    (const __attribute__((address_space(1))) void*)g,
                    (__attribute__((address_space(3))) void*)
                        (smem + c * 1024 + lane * 16),
                    16, 0, 0);
            }
        }
        __syncthreads();                 // drains vmcnt; buf visible

#pragma unroll
        for (int kk = 0; kk < 2; ++kk) {
            const int co = kk ? koff1 : koff0;
            bf16x8 af[4], bfr[8], aw;
            aw = *(const bf16x8*)(smem + hi8 * 1024 + s7 * 128 + co);
#pragma unroll
            for (int im = 0; im < 4; ++im)
                af[im] = *(const bf16x8*)(smem +
                    (1 + wave * 8 + im * 2 + hi8) * 1024 + s7 * 128 + co);
#pragma unroll
            for (int in = 0; in < 8; ++in)
                bfr[in] = *(const bf16x8*)(smem +
                    (17 + in * 2 + hi8) * 1024 + s7 * 128 + co);
#pragma unroll
            for (int im = 0; im < 4; ++im)
#pragma unroll
                for (int in = 0; in < 8; ++in)
                    acc[im][in] = __builtin_amdgcn_mfma_f32_16x16x32_bf16(
                        af[im], bfr[in], acc[im][in], 0, 0, 0);
            // warm: STATIC indices only (rule #20 -- wave is runtime; branch
            // is wave-uniform so no divergence cost, indices compile-time)
            if (wave == 0) {
#pragma unroll
                for (int j = 0; j < 4; ++j)
                    wacc[j] = __builtin_amdgcn_mfma_f32_16x16x32_bf16(
                        aw, bfr[j], wacc[j], 0, 0, 0);
            } else {
#pragma unroll
                for (int j = 0; j < 4; ++j)
                    wacc[j] = __builtin_amdgcn_mfma_f32_16x16x32_bf16(
                        aw, bfr[4 + j], wacc[j], 0, 0, 0);
            }
        }
        __syncthreads();                 // reads done -> next stage may clobber
    }

    // ---- epilogue: S (bf16) -> LDS rows 0..135 stride 132 ----
    // LDS row l = global row m0-8+l (rows 0..7 warm).
    unsigned short* Sl = (unsigned short*)smem;
#pragma unroll
    for (int im = 0; im < 4; ++im)
#pragma unroll
        for (int in = 0; in < 8; ++in) {
            const int col = in * 16 + l16;
#pragma unroll
            for (int r = 0; r < 4; ++r) {
                const int row = 8 + wave * 64 + im * 16 + quad * 4 + r;
                Sl[row * 132 + col] = f2bf(acc[im][in][r]);
            }
        }
    if (quad < 2) {                      // warm rows 0..7 (wacc rows 0..7)
#pragma unroll
        for (int j = 0; j < 4; ++j) {
            const int col = wave * 64 + j * 16 + l16;
#pragma unroll
            for (int r = 0; r < 4; ++r)
                Sl[(quad * 4 + r) * 132 + col] = f2bf(wacc[j][r]);
        }
    }
    __syncthreads();

    // ---- in-block scan: 128 cols x 128 rows ----
    const int c = tid;                   // 0..127
    const float aa = Ad[n0 + c];
    float y = 0.f;
    if (mt != 0) {
#pragma unroll
        for (int i = 0; i < 8; ++i)      // warm rows 0..7
            y = fmaf(aa, y, bf2f(Sl[i * 132 + c]));
    }
    const size_t ob = (size_t)m0 * N + n0 + c;
    const unsigned short* Sr = Sl + 8 * 132 + c;
    for (int t = 0; t < 128; ++t) {
        y = fmaf(aa, y, bf2f(Sr[t * 132]));
        out[ob + (size_t)t * N] = y;
    }
}

// ---------------- tier-2 GEMM: 256x128, split-K=2, bf16 out (proven) --------

__global__ __launch_bounds__(256, 2) void gemm_sk_bf16out(
    const unsigned short* __restrict__ A,
    const unsigned short* __restrict__ Bt,
    unsigned short* __restrict__ S0, unsigned short* __restrict__ S1,
    int M, int N, int K, int gridM, int gridN)
{
    __shared__ __attribute__((aligned(16))) unsigned short sA[256 * 64];
    __shared__ __attribute__((aligned(16))) unsigned short sB[128 * 64];

    const int tid  = threadIdx.x;
    const int wave = tid >> 6;
    const int lane = tid & 63;

    int b = blockIdx.x;
    int mt, nt, kt;
    if ((gridM & 7) == 0) {
        int x = b & 7, g = b >> 3;
        int mPerX = gridM >> 3;
        int ml = g % mPerX, g2 = g / mPerX;
        nt = g2 % gridN;
        kt = g2 / gridN;
        mt = x * mPerX + ml;
    } else {
        mt = b % gridM;
        nt = (b / gridM) % gridN;
        kt = b / (gridM * gridN);
    }
    const int m0 = mt * 256;
    const int n0 = nt * 128;
    const int ksize = K / 2;
    const int kbase = kt * ksize;

    const int srow = lane >> 3;
    const int scol = ((lane & 7) ^ srow) * 8;

    const int quad = lane >> 4;
    const int l16  = lane & 15;
    const int wm = wave >> 1;
    const int wn = wave & 1;
    const int s7 = l16 & 7;
    const int c0 = (quad ^ s7) * 16;
    const int c1 = ((quad + 4) ^ s7) * 16;

    f32x4 acc[8][4];
#pragma unroll
    for (int i = 0; i < 8; ++i)
#pragma unroll
        for (int j = 0; j < 4; ++j)
            acc[i][j] = (f32x4){0.f, 0.f, 0.f, 0.f};

    const unsigned short* Ab = A  + (size_t)m0 * K;
    const unsigned short* Bb = Bt + (size_t)n0 * K;

    const int rA = (wm * 16 + (l16 >> 3)) * 1024 + s7 * 128;
    const int rB = (wn * 8  + (l16 >> 3)) * 1024 + s7 * 128;

    for (int k0 = kbase; k0 < kbase + ksize; k0 += 64) {
#pragma unroll
        for (int i = 0; i < 8; ++i) {
            const int t = wave * 8 + i;
            const unsigned short* ga = Ab + (size_t)(t * 8 + srow) * K + (k0 + scol);
            __builtin_amdgcn_global_load_lds(
                (const __attribute__((address_space(1))) void*)ga,
                (__attribute__((address_space(3))) void*)(sA + t * 512),
                16, 0, 0);
        }
#pragma unroll
        for (int i = 0; i < 4; ++i) {
            const int t = wave * 4 + i;
            const unsigned short* gb = Bb + (size_t)(t * 8 + srow) * K + (k0 + scol);
            __builtin_amdgcn_global_load_lds(
                (const __attribute__((address_space(1))) void*)gb,
                (__attribute__((address_space(3))) void*)(sB + t * 512),
                16, 0, 0);
        }
        __syncthreads();

#pragma unroll
        for (int kk = 0; kk < 2; ++kk) {
            const int co = kk ? c1 : c0;
            bf16x8 af[8], bfr[4];
#pragma unroll
            for (int im = 0; im < 8; ++im)
                af[im] = *(const bf16x8*)((const char*)sA + rA + im * 2048 + co);
#pragma unroll
            for (int in = 0; in < 4; ++in)
                bfr[in] = *(const bf16x8*)((const char*)sB + rB + in * 2048 + co);
#pragma unroll
            for (int im = 0; im < 8; ++im)
#pragma unroll
                for (int in = 0; in < 4; ++in)
                    acc[im][in] = __builtin_amdgcn_mfma_f32_16x16x32_bf16(
                        af[im], bfr[in], acc[im][in], 0, 0, 0);
        }
        __syncthreads();
    }

    unsigned short* __restrict__ S = (kt == 0) ? S0 : S1;
#pragma unroll
    for (int im = 0; im < 8; ++im) {
#pragma unroll
        for (int in = 0; in < 4; ++in) {
            int col = n0 + wn * 64 + in * 16 + l16;
#pragma unroll
            for (int r = 0; r < 4; ++r) {
                int row = m0 + wm * 128 + im * 16 + quad * 4 + r;
                S[(size_t)row * N + col] = f2bf(acc[im][in][r]);
            }
        }
    }
}

// ---------------- mid-tier GEMM (fp32 out, non-split; round-3 proven) -------

__device__ __forceinline__ void stage_tile128(
    const unsigned short* __restrict__ Ab, const unsigned short* __restrict__ Bb,
    unsigned short* sAp, unsigned short* sBp,
    int wave, int srow, int scol, int k0, int K)
{
#pragma unroll
    for (int i = 0; i < 4; ++i) {
        const int t = wave * 4 + i;
        const unsigned short* ga = Ab + (size_t)(t * 8 + srow) * K + (k0 + scol);
        __builtin_amdgcn_global_load_lds(
            (const __attribute__((address_space(1))) void*)ga,
            (__attribute__((address_space(3))) void*)(sAp + t * 512),
            16, 0, 0);
        const unsigned short* gb = Bb + (size_t)(t * 8 + srow) * K + (k0 + scol);
        __builtin_amdgcn_global_load_lds(
            (const __attribute__((address_space(1))) void*)gb,
            (__attribute__((address_space(3))) void*)(sBp + t * 512),
            16, 0, 0);
    }
}

__global__ __launch_bounds__(256, 4) void gemm_f32out(
    const unsigned short* __restrict__ A,
    const unsigned short* __restrict__ Bt,
    float* __restrict__ C, int M, int N, int K, int gridM)
{
    __shared__ __attribute__((aligned(16))) unsigned short sA[128 * 64];
    __shared__ __attribute__((aligned(16))) unsigned short sB[128 * 64];

    const int tid  = threadIdx.x;
    const int wave = tid >> 6;
    const int lane = tid & 63;

    int b = blockIdx.x;
    int mt, nt;
    if ((gridM & 7) == 0) {
        int x = b & 7, g = b >> 3;
        int mPerX = gridM >> 3;
        mt = x * mPerX + (g % mPerX);
        nt = g / mPerX;
    } else {
        mt = b % gridM;
        nt = b / gridM;
    }
    const int m0 = mt * 128;
    const int n0 = nt * 128;

    const int srow = lane >> 3;
    const int scol = ((lane & 7) ^ srow) * 8;
    const int quad = lane >> 4;
    const int l16  = lane & 15;
    const int wm = wave >> 1;
    const int wn = wave & 1;
    const int s7 = l16 & 7;
    const int rbaseA = (wm * 8 + (l16 >> 3)) * 1024 + s7 * 128;
    const int rbaseB = (wn * 8 + (l16 >> 3)) * 1024 + s7 * 128;
    const int coff0 = (quad ^ s7) * 16;
    const int coff1 = ((quad + 4) ^ s7) * 16;

    f32x4 acc[4][4];
#pragma unroll
    for (int i = 0; i < 4; ++i)
#pragma unroll
        for (int j = 0; j < 4; ++j)
            acc[i][j] = (f32x4){0.f, 0.f, 0.f, 0.f};

    const unsigned short* Ab = A  + (size_t)m0 * K;
    const unsigned short* Bb = Bt + (size_t)n0 * K;

    for (int k0 = 0; k0 < K; k0 += 64) {
        stage_tile128(Ab, Bb, sA, sB, wave, srow, scol, k0, K);
        __syncthreads();
        bf16x8 af[2][4], bfr[2][4];
#pragma unroll
        for (int t = 0; t < 4; ++t) {
            const char* pa = (const char*)sA + rbaseA + t * 2048;
            af[0][t]  = *(const bf16x8*)(pa + coff0);
            af[1][t]  = *(const bf16x8*)(pa + coff1);
            const char* pb = (const char*)sB + rbaseB + t * 2048;
            bfr[0][t] = *(const bf16x8*)(pb + coff0);
            bfr[1][t] = *(const bf16x8*)(pb + coff1);
        }
#pragma unroll
        for (int kk = 0; kk < 2; ++kk)
#pragma unroll
            for (int im = 0; im < 4; ++im)
#pragma unroll
                for (int in = 0; in < 4; ++in)
                    acc[im][in] = __builtin_amdgcn_mfma_f32_16x16x32_bf16(
                        af[kk][im], bfr[kk][in], acc[im][in], 0, 0, 0);
        __syncthreads();
    }

#pragma unroll
    for (int im = 0; im < 4; ++im)
#pragma unroll
        for (int in = 0; in < 4; ++in) {
            int col = n0 + wn * 64 + in * 16 + l16;
#pragma unroll
            for (int r = 0; r < 4; ++r) {
                int row = m0 + wm * 64 + im * 16 + quad * 4 + r;
                C[(size_t)row * N + col] = acc[im][in][r];
            }
        }
}

// ---------------- scan (split-K fallback path) ----------------

__global__ void scan_splitk_bf16(const unsigned short* __restrict__ S0,
                                 const unsigned short* __restrict__ S1,
                                 const float* __restrict__ a_diag,
                                 float* __restrict__ out,
                                 int H2, int chunk) {
    int tid = blockIdx.x * blockDim.x + threadIdx.x;
    int hp = tid % H2, c = tid / H2;
    float2 av = ((const float2*)a_diag)[hp];
    const ushort2* S0v = (const ushort2*)S0;
    const ushort2* S1v = (const ushort2*)S1;
    float2* outv = (float2*)out;

    float y0 = 0.f, y1 = 0.f;
    if (c > 0) {
        size_t r0 = (size_t)c * chunk - 8;
#pragma unroll
        for (int i = 0; i < 8; ++i) {
            size_t idx = (r0 + i) * H2 + hp;
            ushort2 u = S0v[idx], w = S1v[idx];
            y0 = fmaf(av.x, y0, bf2f(u.x) + bf2f(w.x));
            y1 = fmaf(av.y, y1, bf2f(u.y) + bf2f(w.y));
        }
    }
    size_t idx = (size_t)c * chunk * H2 + hp;
    ushort2 u = S0v[idx], w = S1v[idx];
    for (int t = 0; t < chunk - 1; ++t) {
        size_t idx2 = idx + H2;
        ushort2 un = S0v[idx2], wn = S1v[idx2];
        y0 = fmaf(av.x, y0, bf2f(u.x) + bf2f(w.x));
        y1 = fmaf(av.y, y1, bf2f(u.y) + bf2f(w.y));
        outv[idx] = make_float2(y0, y1);
        u = un; w = wn; idx = idx2;
    }
    y0 = fmaf(av.x, y0, bf2f(u.x) + bf2f(w.x));
    y1 = fmaf(av.y, y1, bf2f(u.y) + bf2f(w.y));
    outv[idx] = make_float2(y0, y1);
}

// ---------------- mid-tier scan (fp32 S in out, in-place) --------------

__global__ void scan_init_kernel(const float* __restrict__ S,
                                 const float* __restrict__ a_diag,
                                 float* __restrict__ yinit,
                                 int H, int chunk, int W) {
    int tid = blockIdx.x * blockDim.x + threadIdx.x;
    int h = tid % H, c = tid / H;
    float a = a_diag[h];
    float y = 0.f;
    if (c > 0) {
        int t0 = c * chunk;
        for (int t = t0 - W; t < t0; ++t)
            y = fmaf(a, y, S[(size_t)t * H + h]);
    }
    yinit[(size_t)c * H + h] = y;
}

__global__ void scan_run_kernel(const float* __restrict__ yinit,
                                const float* __restrict__ a_diag,
                                float* __restrict__ out,
                                int H, int chunk) {
    int tid = blockIdx.x * blockDim.x + threadIdx.x;
    int h = tid % H, c = tid / H;
    float a = a_diag[h];
    float y = yinit[(size_t)c * H + h];
    size_t base = (size_t)c * chunk * H + h;
    float s = out[base];
#pragma unroll 4
    for (int t = 0; t < chunk - 1; ++t) {
        float snext = out[base + (size_t)(t + 1) * H];
        y = fmaf(a, y, s);
        out[base + (size_t)t * H] = y;
        s = snext;
    }
    y = fmaf(a, y, s);
    out[base + (size_t)(chunk - 1) * H] = y;
}

// ---------------- fallback (tiny ws): correct but slow ----------------

__global__ void gemm_fallback(const float* __restrict__ X, const float* __restrict__ B,
                              float* __restrict__ C, int M, int N, int K) {
    __shared__ float sA[16][17];
    __shared__ float sB[16][17];
    int tx = threadIdx.x, ty = threadIdx.y;
    int row = blockIdx.y * 16 + ty, col = blockIdx.x * 16 + tx;
    float acc = 0.f;
    for (int k0 = 0; k0 < K; k0 += 16) {
        sA[ty][tx] = (row < M && k0 + tx < K) ? X[(size_t)row * K + k0 + tx] : 0.f;
        sB[ty][tx] = (k0 + ty < K && col < N) ? B[(size_t)(k0 + ty) * N + col] : 0.f;
        __syncthreads();
#pragma unroll
        for (int kk = 0; kk < 16; ++kk) acc += sA[ty][kk] * sB[kk][tx];
        __syncthreads();
    }
    if (row < M && col < N) C[(size_t)row * N + col] = acc;
}

__global__ void scan_serial(float* __restrict__ out, const float* __restrict__ a_diag,
                            int T, int H) {
    int h = blockIdx.x * blockDim.x + threadIdx.x;
    if (h >= H) return;
    float a = a_diag[h], y = 0.f;
    for (int t = 0; t < T; ++t) {
        y = fmaf(a, y, out[(size_t)t * H + h]);
        out[(size_t)t * H + h] = y;
    }
}

// ---------------- launch ----------------

extern "C" void kernel_launch(void* const* d_in, const int* in_sizes, int n_in,
                              void* d_out, int out_size, void* d_ws, size_t ws_size,
                              hipStream_t stream) {
    const float* x = (const float*)d_in[0];   // (T,H)
    const float* a = (const float*)d_in[1];   // (H,)
    const float* b = (const float*)d_in[2];   // (H,H)
    float* out = (float*)d_out;               // (T,H)

    const int H = in_sizes[1];
    const int T = in_sizes[0] / H;
    const int M = T, N = H, K = H;

    const int CHUNK = 16, W = 12;

    size_t xbf_elems = (size_t)M * K;
    size_t bt_elems  = (size_t)N * K;
    size_t MN = (size_t)M * N;
    int nchunks = (T % CHUNK == 0) ? T / CHUNK : 0;

    size_t need_fused = (xbf_elems + bt_elems) * 2 + 256;
    size_t need_sk  = (xbf_elems + bt_elems + 2 * MN) * 2 + 256;
    size_t need_mid = xbf_elems * 2 + bt_elems * 2 + 256;

    bool shape_ok = (M % 128 == 0) && (N % 128 == 0) && (K % 128 == 0) &&
                    (H % 32 == 0) && nchunks > 0 && ((xbf_elems % 4) == 0) &&
                    (((size_t)nchunks * H) % 256 == 0);
    int gridMf = M / 128;
    int gridM  = (M % 256 == 0) ? M / 256 : 0;
    int gridN  = N / 128;

    int n4 = (int)(xbf_elems / 4);
    int castBlocks = (n4 + 255) / 256;
    int transBlocks = (H % 32 == 0) ? (H / 32) * (H / 32) : 0;

    int H2 = H / 2;
    size_t nth2 = (size_t)nchunks * H2;

    bool fused_ok = (M % 128 == 0) && (N % 128 == 0) && (K % 64 == 0) &&
                    (K >= 128) && (H % 32 == 0) && ((xbf_elems % 4) == 0) &&
                    ws_size >= need_fused;

    if (fused_ok) {
        // tier-1: fused full-K GEMM + in-block scan (no S materialization)
        unsigned short* Xbf = (unsigned short*)d_ws;
        unsigned short* Bt  = Xbf + xbf_elems;

        prep_kernel<<<castBlocks + transBlocks, 256, 0, stream>>>(
            x, Xbf, n4, b, Bt, H, castBlocks);

        gemm_scan_fused<<<(M / 128) * (N / 128), 128, 35904, stream>>>(
            Xbf, Bt, a, out, M, N, K, M / 128);
    } else if (shape_ok && gridM > 0 && (gridM % 8 == 0) && (H % 4 == 0) &&
               (nth2 % 256 == 0) && ws_size >= need_sk) {
        // tier-2: 256x128 tiles, split-K=2, bf16 partials, race-free scan
        unsigned short* Xbf = (unsigned short*)d_ws;
        unsigned short* Bt  = Xbf + xbf_elems;
        unsigned short* S0  = Bt + bt_elems;
        unsigned short* S1  = S0 + MN;

        prep_kernel<<<castBlocks + transBlocks, 256, 0, stream>>>(
            x, Xbf, n4, b, Bt, H, castBlocks);

        gemm_sk_bf16out<<<gridM * gridN * 2, 256, 0, stream>>>(
            Xbf, Bt, S0, S1, M, N, K, gridM, gridN);

        scan_splitk_bf16<<<(int)(nth2 / 256), 256, 0, stream>>>(
            S0, S1, a, out, H2, CHUNK);
    } else if (shape_ok && ws_size >= need_mid &&
               ((size_t)nchunks * H * 4 <= xbf_elems * 2)) {
        unsigned short* Xbf = (unsigned short*)d_ws;
        unsigned short* Bt  = Xbf + xbf_elems;
        float* yinit = (float*)d_ws;   // aliases Xbf: dead after gemm reads it

        prep_kernel<<<castBlocks + transBlocks, 256, 0, stream>>>(
            x, Xbf, n4, b, Bt, H, castBlocks);

        gemm_f32out<<<gridMf * gridN, 256, 0, stream>>>(
            Xbf, Bt, out, M, N, K, gridMf);

        int nth = nchunks * H;
        scan_init_kernel<<<nth / 256, 256, 0, stream>>>(out, a, yinit, H, CHUNK, W);
        scan_run_kernel<<<nth / 256, 256, 0, stream>>>(yinit, a, out, H, CHUNK);
    } else {
        dim3 tb(16, 16), tg((N + 15) / 16, (M + 15) / 16);
        gemm_fallback<<<tg, tb, 0, stream>>>(x, b, out, M, N, K);
        scan_serial<<<(H + 255) / 256, 256, 0, stream>>>(out, a, T, H);
    }
}

// Round 9
// 139.532 us; speedup vs baseline: 28.4063x; 2.1634x over previous
//
#include <hip/hip_runtime.h>
#include <cstdint>
#include <cstddef>

typedef short bf16x8 __attribute__((ext_vector_type(8)));
typedef float f32x4 __attribute__((ext_vector_type(4)));

__device__ __forceinline__ unsigned short f2bf(float f) {
    union { float f; uint32_t u; } v; v.f = f;
    uint32_t r = v.u + 0x7FFFu + ((v.u >> 16) & 1u);   // round-to-nearest-even
    return (unsigned short)(r >> 16);
}

__device__ __forceinline__ float bf2f(unsigned short u) {
    union { uint32_t u; float f; } v; v.u = (uint32_t)u << 16;
    return v.f;
}

// ---------------- prep: cast X to bf16  +  transpose-cast B ----------------

__global__ void prep_kernel(const float* __restrict__ X,
                            unsigned short* __restrict__ Xbf, int n4,
                            const float* __restrict__ B,
                            unsigned short* __restrict__ Bt, int H,
                            int castBlocks) {
    if ((int)blockIdx.x < castBlocks) {
        int i = blockIdx.x * 256 + threadIdx.x;
        if (i < n4) {
            float4 v = ((const float4*)X)[i];
            ushort4 o;
            o.x = f2bf(v.x); o.y = f2bf(v.y); o.z = f2bf(v.z); o.w = f2bf(v.w);
            ((ushort4*)Xbf)[i] = o;
        }
        return;
    }
    __shared__ float tile[32][33];
    int tb = blockIdx.x - castBlocks;
    int tilesPerRow = H / 32;
    int bx = (tb % tilesPerRow) * 32;   // n tile
    int by = (tb / tilesPerRow) * 32;   // k tile
    int tx = threadIdx.x & 31, ty = threadIdx.x >> 5;   // (32,8)
#pragma unroll
    for (int i = 0; i < 32; i += 8)
        tile[ty + i][tx] = B[(size_t)(by + ty + i) * H + bx + tx];
    __syncthreads();
#pragma unroll
    for (int i = 0; i < 32; i += 8)
        Bt[(size_t)(bx + ty + i) * H + by + tx] = f2bf(tile[tx][ty + i]);
}

// ---------------- tier-1: fused full-K GEMM + in-block scan (v2c) -----------
// Base = r4's verified v2 (fused 50us, total 137.3us; 128x128 tile, 4 waves
// of 64x64, 2 blk/CU, double-buffered stage-before-compute, 1 barrier/step).
// r8 closure: 128x64 wave tiles are structurally 1 wave/SIMD on this problem
// (1024 waves total) -> latency-exposed regardless of schedule (v3/v4/v5b);
// 64x64 tiles give 8 waves/CU and are LDS-BW-bound. So optimize v2's LDS
// traffic: warm-up reads were aw+bw0+bw1 x 4 waves = 12KB/kk/block. v2c:
// only wm==0 waves compute warm, REUSING their bfr fragments (wacc[in] +=
// aw*bfr[in], static idx, wave-uniform branch) -> warm reads 2KB/kk.
// Total LDS/step/block 121->101KB (-17%); same MFMA count; bit-identical
// numerics (same products, same per-column accumulation order).
// Warm rows 0..7 = global m0-8..m0-1 (chunk 0); wacc rows 8..15 discarded.
// |a| <= 2^-5 -> 8-row replay reconstructs scan carry to ~1e-12.

__global__ __launch_bounds__(256, 2) void gemm_scan_fused(
    const unsigned short* __restrict__ A,
    const unsigned short* __restrict__ Bt,
    const float* __restrict__ Ad,
    float* __restrict__ out,
    int M, int N, int K, int gridMt)
{
    extern __shared__ char smem[];   // 67584 B dynamic (2 x 33 chunks)

    const int tid  = threadIdx.x;
    const int wave = tid >> 6;
    const int lane = tid & 63;

    int b = blockIdx.x;
    int mt, nt;
    if ((gridMt & 7) == 0) {
        int x = b & 7, g = b >> 3;
        int mPerX = gridMt >> 3;
        mt = x * mPerX + (g % mPerX);
        nt = g / mPerX;
    } else {
        mt = b % gridMt;
        nt = b / gridMt;
    }
    const int m0 = mt * 128;
    const int n0 = nt * 128;

    const int wm = wave >> 1;           // 0..1: 64-row group
    const int wn = wave & 1;            // 0..1: 64-col group
    const int srow = lane >> 3;
    const int scol = ((lane & 7) ^ srow) * 8;
    const int quad = lane >> 4;
    const int l16  = lane & 15;
    const int s7   = l16 & 7;
    const int koff0 = (quad ^ s7) * 16;
    const int koff1 = ((quad + 4) ^ s7) * 16;
    const int hi8  = l16 >> 3;

    f32x4 acc[4][4];
#pragma unroll
    for (int i = 0; i < 4; ++i)
#pragma unroll
        for (int j = 0; j < 4; ++j)
            acc[i][j] = (f32x4){0.f, 0.f, 0.f, 0.f};
    f32x4 wacc[4];
#pragma unroll
    for (int j = 0; j < 4; ++j)
        wacc[j] = (f32x4){0.f, 0.f, 0.f, 0.f};

    const int NT = K >> 6;

    // chunk t: t<17 -> A rows m0-8+t*8+srow (clamped); t>=17 -> B rows
    // n0+(t-17)*8+srow. lane l -> slot l*16B, global colblk (l&7)^(l>>3).
    auto STAGE = [&](int bufoff, int k0) {
#pragma unroll
        for (int i = 0; i < 9; ++i) {
            const int t = wave + i * 4;
            if (t < 33) {
                const unsigned short* g;
                if (t < 17) {
                    int gr = m0 - 8 + t * 8 + srow;
                    if (gr < 0) gr = 0;                 // mt==0 warm clamp
                    g = A + (size_t)gr * K + (k0 + scol);
                } else {
                    const int gr = n0 + (t - 17) * 8 + srow;
                    g = Bt + (size_t)gr * K + (k0 + scol);
                }
                __builtin_amdgcn_global_load_lds(
                    (const __attribute__((address_space(1))) void*)g,
                    (__attribute__((address_space(3))) void*)
                        (smem + bufoff + t * 1024 + lane * 16),
                    16, 0, 0);
            }
        }
    };

    STAGE(0, 0);
    __syncthreads();                     // implicit vmcnt(0) drain

    for (int t = 0; t < NT; ++t) {
        const int cur = (t & 1) * 33792;
        if (t + 1 < NT)
            STAGE((~t & 1) * 33792, (t + 1) * 64);   // flies under MFMAs

        const char* base = smem + cur;
#pragma unroll
        for (int kk = 0; kk < 2; ++kk) {
            const int co = kk ? koff1 : koff0;
            bf16x8 af[4], bfr[4];
#pragma unroll
            for (int im = 0; im < 4; ++im)
                af[im] = *(const bf16x8*)(base +
                    (1 + wm * 8 + im * 2 + hi8) * 1024 + s7 * 128 + co);
#pragma unroll
            for (int in = 0; in < 4; ++in)
                bfr[in] = *(const bf16x8*)(base +
                    (17 + wn * 8 + in * 2 + hi8) * 1024 + s7 * 128 + co);
#pragma unroll
            for (int im = 0; im < 4; ++im)
#pragma unroll
                for (int in = 0; in < 4; ++in)
                    acc[im][in] = __builtin_amdgcn_mfma_f32_16x16x32_bf16(
                        af[im], bfr[in], acc[im][in], 0, 0, 0);
            if (wm == 0) {               // warm: reuse bfr, 1 extra read only
                bf16x8 aw = *(const bf16x8*)(base + hi8 * 1024 + s7 * 128 + co);
#pragma unroll
                for (int in = 0; in < 4; ++in)
                    wacc[in] = __builtin_amdgcn_mfma_f32_16x16x32_bf16(
                        aw, bfr[in], wacc[in], 0, 0, 0);
            }
        }
        __syncthreads();                 // drains vmcnt incl. next-tile stage
    }

    // ---- epilogue: S (bf16) -> LDS, stride 132 (quads on banks +0/8/16/24)
    // LDS row 0..7 = warm rows (global m0-8..m0-1); row 8+r = global m0+r.
    unsigned short* Sl = (unsigned short*)smem;
#pragma unroll
    for (int im = 0; im < 4; ++im)
#pragma unroll
        for (int in = 0; in < 4; ++in) {
            const int col = wn * 64 + in * 16 + l16;
#pragma unroll
            for (int r = 0; r < 4; ++r) {
                const int row = 8 + wm * 64 + im * 16 + quad * 4 + r;
                Sl[row * 132 + col] = f2bf(acc[im][in][r]);
            }
        }
    if (wm == 0 && quad < 2) {           // warm rows 0..7 (wacc rows 0..7)
#pragma unroll
        for (int in = 0; in < 4; ++in) {
            const int col = wn * 64 + in * 16 + l16;
#pragma unroll
            for (int r = 0; r < 4; ++r)
                Sl[(quad * 4 + r) * 132 + col] = f2bf(wacc[in][r]);
        }
    }
    __syncthreads();

    // ---- in-block scan: 128 cols x 2 row-halves of 64 ----
    const int c = tid & 127;
    const int q = tid >> 7;
    const float aa = Ad[n0 + c];
    float y = 0.f;
    if (mt != 0 || q != 0) {
#pragma unroll
        for (int i = 0; i < 8; ++i)      // 8 rows before this half
            y = fmaf(aa, y, bf2f(Sl[(q * 64 + i) * 132 + c]));
    }
    const size_t ob = (size_t)(m0 + q * 64) * N + n0 + c;
    const unsigned short* Sr = Sl + (8 + q * 64) * 132 + c;
    for (int t = 0; t < 64; ++t) {
        y = fmaf(aa, y, bf2f(Sr[t * 132]));
        out[ob + (size_t)t * N] = y;
    }
}

// ---------------- tier-2 GEMM: 256x128, split-K=2, bf16 out (proven) --------

__global__ __launch_bounds__(256, 2) void gemm_sk_bf16out(
    const unsigned short* __restrict__ A,
    const unsigned short* __restrict__ Bt,
    unsigned short* __restrict__ S0, unsigned short* __restrict__ S1,
    int M, int N, int K, int gridM, int gridN)
{
    __shared__ __attribute__((aligned(16))) unsigned short sA[256 * 64];
    __shared__ __attribute__((aligned(16))) unsigned short sB[128 * 64];

    const int tid  = threadIdx.x;
    const int wave = tid >> 6;
    const int lane = tid & 63;

    int b = blockIdx.x;
    int mt, nt, kt;
    if ((gridM & 7) == 0) {
        int x = b & 7, g = b >> 3;
        int mPerX = gridM >> 3;
        int ml = g % mPerX, g2 = g / mPerX;
        nt = g2 % gridN;
        kt = g2 / gridN;
        mt = x * mPerX + ml;
    } else {
        mt = b % gridM;
        nt = (b / gridM) % gridN;
        kt = b / (gridM * gridN);
    }
    const int m0 = mt * 256;
    const int n0 = nt * 128;
    const int ksize = K / 2;
    const int kbase = kt * ksize;

    const int srow = lane >> 3;
    const int scol = ((lane & 7) ^ srow) * 8;

    const int quad = lane >> 4;
    const int l16  = lane & 15;
    const int wm = wave >> 1;
    const int wn = wave & 1;
    const int s7 = l16 & 7;
    const int c0 = (quad ^ s7) * 16;
    const int c1 = ((quad + 4) ^ s7) * 16;

    f32x4 acc[8][4];
#pragma unroll
    for (int i = 0; i < 8; ++i)
#pragma unroll
        for (int j = 0; j < 4; ++j)
            acc[i][j] = (f32x4){0.f, 0.f, 0.f, 0.f};

    const unsigned short* Ab = A  + (size_t)m0 * K;
    const unsigned short* Bb = Bt + (size_t)n0 * K;

    const int rA = (wm * 16 + (l16 >> 3)) * 1024 + s7 * 128;
    const int rB = (wn * 8  + (l16 >> 3)) * 1024 + s7 * 128;

    for (int k0 = kbase; k0 < kbase + ksize; k0 += 64) {
#pragma unroll
        for (int i = 0; i < 8; ++i) {
            const int t = wave * 8 + i;
            const unsigned short* ga = Ab + (size_t)(t * 8 + srow) * K + (k0 + scol);
            __builtin_amdgcn_global_load_lds(
                (const __attribute__((address_space(1))) void*)ga,
                (__attribute__((address_space(3))) void*)(sA + t * 512),
                16, 0, 0);
        }
#pragma unroll
        for (int i = 0; i < 4; ++i) {
            const int t = wave * 4 + i;
            const unsigned short* gb = Bb + (size_t)(t * 8 + srow) * K + (k0 + scol);
            __builtin_amdgcn_global_load_lds(
                (const __attribute__((address_space(1))) void*)gb,
                (__attribute__((address_space(3))) void*)(sB + t * 512),
                16, 0, 0);
        }
        __syncthreads();

#pragma unroll
        for (int kk = 0; kk < 2; ++kk) {
            const int co = kk ? c1 : c0;
            bf16x8 af[8], bfr[4];
#pragma unroll
            for (int im = 0; im < 8; ++im)
                af[im] = *(const bf16x8*)((const char*)sA + rA + im * 2048 + co);
#pragma unroll
            for (int in = 0; in < 4; ++in)
                bfr[in] = *(const bf16x8*)((const char*)sB + rB + in * 2048 + co);
#pragma unroll
            for (int im = 0; im < 8; ++im)
#pragma unroll
                for (int in = 0; in < 4; ++in)
                    acc[im][in] = __builtin_amdgcn_mfma_f32_16x16x32_bf16(
                        af[im], bfr[in], acc[im][in], 0, 0, 0);
        }
        __syncthreads();
    }

    unsigned short* __restrict__ S = (kt == 0) ? S0 : S1;
#pragma unroll
    for (int im = 0; im < 8; ++im) {
#pragma unroll
        for (int in = 0; in < 4; ++in) {
            int col = n0 + wn * 64 + in * 16 + l16;
#pragma unroll
            for (int r = 0; r < 4; ++r) {
                int row = m0 + wm * 128 + im * 16 + quad * 4 + r;
                S[(size_t)row * N + col] = f2bf(acc[im][in][r]);
            }
        }
    }
}

// ---------------- mid-tier GEMM (fp32 out, non-split; round-3 proven) -------

__device__ __forceinline__ void stage_tile128(
    const unsigned short* __restrict__ Ab, const unsigned short* __restrict__ Bb,
    unsigned short* sAp, unsigned short* sBp,
    int wave, int srow, int scol, int k0, int K)
{
#pragma unroll
    for (int i = 0; i < 4; ++i) {
        const int t = wave * 4 + i;
        const unsigned short* ga = Ab + (size_t)(t * 8 + srow) * K + (k0 + scol);
        __builtin_amdgcn_global_load_lds(
            (const __attribute__((address_space(1))) void*)ga,
            (__attribute__((address_space(3))) void*)(sAp + t * 512),
            16, 0, 0);
        const unsigned short* gb = Bb + (size_t)(t * 8 + srow) * K + (k0 + scol);
        __builtin_amdgcn_global_load_lds(
            (const __attribute__((address_space(1))) void*)gb,
            (__attribute__((address_space(3))) void*)(sBp + t * 512),
            16, 0, 0);
    }
}

__global__ __launch_bounds__(256, 4) void gemm_f32out(
    const unsigned short* __restrict__ A,
    const unsigned short* __restrict__ Bt,
    float* __restrict__ C, int M, int N, int K, int gridM)
{
    __shared__ __attribute__((aligned(16))) unsigned short sA[128 * 64];
    __shared__ __attribute__((aligned(16))) unsigned short sB[128 * 64];

    const int tid  = threadIdx.x;
    const int wave = tid >> 6;
    const int lane = tid & 63;

    int b = blockIdx.x;
    int mt, nt;
    if ((gridM & 7) == 0) {
        int x = b & 7, g = b >> 3;
        int mPerX = gridM >> 3;
        mt = x * mPerX + (g % mPerX);
        nt = g / mPerX;
    } else {
        mt = b % gridM;
        nt = b / gridM;
    }
    const int m0 = mt * 128;
    const int n0 = nt * 128;

    const int srow = lane >> 3;
    const int scol = ((lane & 7) ^ srow) * 8;
    const int quad = lane >> 4;
    const int l16  = lane & 15;
    const int wm = wave >> 1;
    const int wn = wave & 1;
    const int s7 = l16 & 7;
    const int rbaseA = (wm * 8 + (l16 >> 3)) * 1024 + s7 * 128;
    const int rbaseB = (wn * 8 + (l16 >> 3)) * 1024 + s7 * 128;
    const int coff0 = (quad ^ s7) * 16;
    const int coff1 = ((quad + 4) ^ s7) * 16;

    f32x4 acc[4][4];
#pragma unroll
    for (int i = 0; i < 4; ++i)
#pragma unroll
        for (int j = 0; j < 4; ++j)
            acc[i][j] = (f32x4){0.f, 0.f, 0.f, 0.f};

    const unsigned short* Ab = A  + (size_t)m0 * K;
    const unsigned short* Bb = Bt + (size_t)n0 * K;

    for (int k0 = 0; k0 < K; k0 += 64) {
        stage_tile128(Ab, Bb, sA, sB, wave, srow, scol, k0, K);
        __syncthreads();
        bf16x8 af[2][4], bfr[2][4];
#pragma unroll
        for (int t = 0; t < 4; ++t) {
            const char* pa = (const char*)sA + rbaseA + t * 2048;
            af[0][t]  = *(const bf16x8*)(pa + coff0);
            af[1][t]  = *(const bf16x8*)(pa + coff1);
            const char* pb = (const char*)sB + rbaseB + t * 2048;
            bfr[0][t] = *(const bf16x8*)(pb + coff0);
            bfr[1][t] = *(const bf16x8*)(pb + coff1);
        }
#pragma unroll
        for (int kk = 0; kk < 2; ++kk)
#pragma unroll
            for (int im = 0; im < 4; ++im)
#pragma unroll
                for (int in = 0; in < 4; ++in)
                    acc[im][in] = __builtin_amdgcn_mfma_f32_16x16x32_bf16(
                        af[kk][im], bfr[kk][in], acc[im][in], 0, 0, 0);
        __syncthreads();
    }

#pragma unroll
    for (int im = 0; im < 4; ++im)
#pragma unroll
        for (int in = 0; in < 4; ++in) {
            int col = n0 + wn * 64 + in * 16 + l16;
#pragma unroll
            for (int r = 0; r < 4; ++r) {
                int row = m0 + wm * 64 + im * 16 + quad * 4 + r;
                C[(size_t)row * N + col] = acc[im][in][r];
            }
        }
}

// ---------------- scan (split-K fallback path) ----------------

__global__ void scan_splitk_bf16(const unsigned short* __restrict__ S0,
                                 const unsigned short* __restrict__ S1,
                                 const float* __restrict__ a_diag,
                                 float* __restrict__ out,
                                 int H2, int chunk) {
    int tid = blockIdx.x * blockDim.x + threadIdx.x;
    int hp = tid % H2, c = tid / H2;
    float2 av = ((const float2*)a_diag)[hp];
    const ushort2* S0v = (const ushort2*)S0;
    const ushort2* S1v = (const ushort2*)S1;
    float2* outv = (float2*)out;

    float y0 = 0.f, y1 = 0.f;
    if (c > 0) {
        size_t r0 = (size_t)c * chunk - 8;
#pragma unroll
        for (int i = 0; i < 8; ++i) {
            size_t idx = (r0 + i) * H2 + hp;
            ushort2 u = S0v[idx], w = S1v[idx];
            y0 = fmaf(av.x, y0, bf2f(u.x) + bf2f(w.x));
            y1 = fmaf(av.y, y1, bf2f(u.y) + bf2f(w.y));
        }
    }
    size_t idx = (size_t)c * chunk * H2 + hp;
    ushort2 u = S0v[idx], w = S1v[idx];
    for (int t = 0; t < chunk - 1; ++t) {
        size_t idx2 = idx + H2;
        ushort2 un = S0v[idx2], wn = S1v[idx2];
        y0 = fmaf(av.x, y0, bf2f(u.x) + bf2f(w.x));
        y1 = fmaf(av.y, y1, bf2f(u.y) + bf2f(w.y));
        outv[idx] = make_float2(y0, y1);
        u = un; w = wn; idx = idx2;
    }
    y0 = fmaf(av.x, y0, bf2f(u.x) + bf2f(w.x));
    y1 = fmaf(av.y, y1, bf2f(u.y) + bf2f(w.y));
    outv[idx] = make_float2(y0, y1);
}

// ---------------- mid-tier scan (fp32 S in out, in-place) --------------

__global__ void scan_init_kernel(const float* __restrict__ S,
                                 const float* __restrict__ a_diag,
                                 float* __restrict__ yinit,
                                 int H, int chunk, int W) {
    int tid = blockIdx.x * blockDim.x + threadIdx.x;
    int h = tid % H, c = tid / H;
    float a = a_diag[h];
    float y = 0.f;
    if (c > 0) {
        int t0 = c * chunk;
        for (int t = t0 - W; t < t0; ++t)
            y = fmaf(a, y, S[(size_t)t * H + h]);
    }
    yinit[(size_t)c * H + h] = y;
}

__global__ void scan_run_kernel(const float* __restrict__ yinit,
                                const float* __restrict__ a_diag,
                                float* __restrict__ out,
                                int H, int chunk) {
    int tid = blockIdx.x * blockDim.x + threadIdx.x;
    int h = tid % H, c = tid / H;
    float a = a_diag[h];
    float y = yinit[(size_t)c * H + h];
    size_t base = (size_t)c * chunk * H + h;
    float s = out[base];
#pragma unroll 4
    for (int t = 0; t < chunk - 1; ++t) {
        float snext = out[base + (size_t)(t + 1) * H];
        y = fmaf(a, y, s);
        out[base + (size_t)t * H] = y;
        s = snext;
    }
    y = fmaf(a, y, s);
    out[base + (size_t)(chunk - 1) * H] = y;
}

// ---------------- fallback (tiny ws): correct but slow ----------------

__global__ void gemm_fallback(const float* __restrict__ X, const float* __restrict__ B,
                              float* __restrict__ C, int M, int N, int K) {
    __shared__ float sA[16][17];
    __shared__ float sB[16][17];
    int tx = threadIdx.x, ty = threadIdx.y;
    int row = blockIdx.y * 16 + ty, col = blockIdx.x * 16 + tx;
    float acc = 0.f;
    for (int k0 = 0; k0 < K; k0 += 16) {
        sA[ty][tx] = (row < M && k0 + tx < K) ? X[(size_t)row * K + k0 + tx] : 0.f;
        sB[ty][tx] = (k0 + ty < K && col < N) ? B[(size_t)(k0 + ty) * N + col] : 0.f;
        __syncthreads();
#pragma unroll
        for (int kk = 0; kk < 16; ++kk) acc += sA[ty][kk] * sB[kk][tx];
        __syncthreads();
    }
    if (row < M && col < N) C[(size_t)row * N + col] = acc;
}

__global__ void scan_serial(float* __restrict__ out, const float* __restrict__ a_diag,
                            int T, int H) {
    int h = blockIdx.x * blockDim.x + threadIdx.x;
    if (h >= H) return;
    float a = a_diag[h], y = 0.f;
    for (int t = 0; t < T; ++t) {
        y = fmaf(a, y, out[(size_t)t * H + h]);
        out[(size_t)t * H + h] = y;
    }
}

// ---------------- launch ----------------

extern "C" void kernel_launch(void* const* d_in, const int* in_sizes, int n_in,
                              void* d_out, int out_size, void* d_ws, size_t ws_size,
                              hipStream_t stream) {
    const float* x = (const float*)d_in[0];   // (T,H)
    const float* a = (const float*)d_in[1];   // (H,)
    const float* b = (const float*)d_in[2];   // (H,H)
    float* out = (float*)d_out;               // (T,H)

    const int H = in_sizes[1];
    const int T = in_sizes[0] / H;
    const int M = T, N = H, K = H;

    const int CHUNK = 16, W = 12;

    size_t xbf_elems = (size_t)M * K;
    size_t bt_elems  = (size_t)N * K;
    size_t MN = (size_t)M * N;
    int nchunks = (T % CHUNK == 0) ? T / CHUNK : 0;

    size_t need_fused = (xbf_elems + bt_elems) * 2 + 256;
    size_t need_sk  = (xbf_elems + bt_elems + 2 * MN) * 2 + 256;
    size_t need_mid = xbf_elems * 2 + bt_elems * 2 + 256;

    bool shape_ok = (M % 128 == 0) && (N % 128 == 0) && (K % 128 == 0) &&
                    (H % 32 == 0) && nchunks > 0 && ((xbf_elems % 4) == 0) &&
                    (((size_t)nchunks * H) % 256 == 0);
    int gridMf = M / 128;
    int gridM  = (M % 256 == 0) ? M / 256 : 0;
    int gridN  = N / 128;

    int n4 = (int)(xbf_elems / 4);
    int castBlocks = (n4 + 255) / 256;
    int transBlocks = (H % 32 == 0) ? (H / 32) * (H / 32) : 0;

    int H2 = H / 2;
    size_t nth2 = (size_t)nchunks * H2;

    bool fused_ok = (M % 128 == 0) && (N % 128 == 0) && (K % 64 == 0) &&
                    (K >= 128) && (H % 32 == 0) && ((xbf_elems % 4) == 0) &&
                    ws_size >= need_fused;

    if (fused_ok) {
        // tier-1: fused full-K GEMM + in-block scan (no S materialization)
        unsigned short* Xbf = (unsigned short*)d_ws;
        unsigned short* Bt  = Xbf + xbf_elems;

        static bool gfattr = false;
        if (!gfattr) {
            (void)hipFuncSetAttribute((const void*)gemm_scan_fused,
                                      hipFuncAttributeMaxDynamicSharedMemorySize,
                                      67584);
            gfattr = true;
        }

        prep_kernel<<<castBlocks + transBlocks, 256, 0, stream>>>(
            x, Xbf, n4, b, Bt, H, castBlocks);

        gemm_scan_fused<<<(M / 128) * (N / 128), 256, 67584, stream>>>(
            Xbf, Bt, a, out, M, N, K, M / 128);
    } else if (shape_ok && gridM > 0 && (gridM % 8 == 0) && (H % 4 == 0) &&
               (nth2 % 256 == 0) && ws_size >= need_sk) {
        // tier-2: 256x128 tiles, split-K=2, bf16 partials, race-free scan
        unsigned short* Xbf = (unsigned short*)d_ws;
        unsigned short* Bt  = Xbf + xbf_elems;
        unsigned short* S0  = Bt + bt_elems;
        unsigned short* S1  = S0 + MN;

        prep_kernel<<<castBlocks + transBlocks, 256, 0, stream>>>(
            x, Xbf, n4, b, Bt, H, castBlocks);

        gemm_sk_bf16out<<<gridM * gridN * 2, 256, 0, stream>>>(
            Xbf, Bt, S0, S1, M, N, K, gridM, gridN);

        scan_splitk_bf16<<<(int)(nth2 / 256), 256, 0, stream>>>(
            S0, S1, a, out, H2, CHUNK);
    } else if (shape_ok && ws_size >= need_mid &&
               ((size_t)nchunks * H * 4 <= xbf_elems * 2)) {
        unsigned short* Xbf = (unsigned short*)d_ws;
        unsigned short* Bt  = Xbf + xbf_elems;
        float* yinit = (float*)d_ws;   // aliases Xbf: dead after gemm reads it

        prep_kernel<<<castBlocks + transBlocks, 256, 0, stream>>>(
            x, Xbf, n4, b, Bt, H, castBlocks);

        gemm_f32out<<<gridMf * gridN, 256, 0, stream>>>(
            Xbf, Bt, out, M, N, K, gridMf);

        int nth = nchunks * H;
        scan_init_kernel<<<nth / 256, 256, 0, stream>>>(out, a, yinit, H, CHUNK, W);
        scan_run_kernel<<<nth / 256, 256, 0, stream>>>(yinit, a, out, H, CHUNK);
    } else {
        dim3 tb(16, 16), tg((N + 15) / 16, (M + 15) / 16);
        gemm_fallback<<<tg, tb, 0, stream>>>(x, b, out, M, N, K);
        scan_serial<<<(H + 255) / 256, 256, 0, stream>>>(out, a, T, H);
    }
}